// Round 23
// baseline (198.650 us; speedup 1.0000x reference)
//
#include <hip/hip_runtime.h>

constexpr int IN_C   = 3;
constexpr int OUT_C  = 64;
constexpr int NB     = 27;
constexpr int CR     = 8192;             // clusters per range (128 KB LDS bins)
constexpr int NS     = 10;               // point slices; R*NS = 250 blocks (1/CU)
constexpr int WQ     = 768;              // per-wave queue entries (mean 514 + 11 sigma)
constexpr int NW     = 8;                // waves per poolscan block (512 threads)
constexpr int WPK_N  = 12 * 64 * 8;      // 6144 bf16 fragment elements

typedef float f32x4 __attribute__((ext_vector_type(4)));
typedef short bf16x8 __attribute__((ext_vector_type(8)));

__device__ __forceinline__ unsigned short f2bf(float f) {
    unsigned u = __builtin_bit_cast(unsigned, f);
    u += 0x7fffu + ((u >> 16) & 1u);     // round-to-nearest-even
    return (unsigned short)(u >> 16);
}
__device__ __forceinline__ float bf2f(unsigned short v) {
    return __builtin_bit_cast(float, (unsigned)v << 16);
}
__device__ __forceinline__ float bflo(unsigned u) {
    return __builtin_bit_cast(float, u << 16);
}
__device__ __forceinline__ float bfhi(unsigned u) {
    return __builtin_bit_cast(float, u & 0xffff0000u);
}

// ---- stage A (+fold in last block): range binning, per-wave queues ----
__global__ __launch_bounds__(512) void
k_poolscan(const int* __restrict__ cluster, const float* __restrict__ x,
           ushort4* __restrict__ partials, int N, int K, int R,
           const float* __restrict__ Wc, const float* __restrict__ Wl,
           unsigned short* __restrict__ Wpk) {
    // ---- fold block: pack W_conv @ W_lin[3:,:] into MFMA B-fragment order ----
    if (blockIdx.x >= (unsigned)(R * NS)) {
        for (int t = threadIdx.x; t < WPK_N; t += 512) {
            int j  = t & 7;
            int l  = (t >> 3) & 63;
            int st = t >> 9;
            int s  = st >> 2, tt = st & 3;
            int kk = 32 * s + 8 * (l >> 4) + j;
            int ch = 16 * tt + (l & 15);
            float acc = 0.f;
            if (kk < NB * IN_C) {
                #pragma unroll
                for (int j2 = 0; j2 < OUT_C; ++j2)
                    acc = fmaf(Wc[kk * 64 + j2], Wl[(IN_C + j2) * OUT_C + ch], acc);
            }
            Wpk[t] = f2bf(acc);
        }
        return;
    }

    __shared__ float bins[CR * 4];       // 128 KB
    __shared__ unsigned qbuf[NW * WQ];   // 24.5 KB: per-wave slices
    const int tid  = threadIdx.x;
    const int wv   = tid >> 6;
    const int lane = tid & 63;
    const int r    = blockIdx.x % R;
    const int s    = blockIdx.x / R;
    const unsigned base = (unsigned)r * CR;
    const unsigned long long lml = (1ull << lane) - 1ull;   // lanemask_lt
    unsigned* __restrict__ wq = qbuf + wv * WQ;

    for (int i = tid; i < CR * 4; i += 512) bins[i] = 0.f;
    __syncthreads();

    const int P4 = N >> 2;               // uint4 count
    const int Q  = P4 / NS;
    const int i0 = s * Q;
    const int i1 = (s == NS - 1) ? P4 : (s + 1) * Q;
    const int niter = (i1 - i0 + 511) >> 9;
    const uint4* __restrict__ cl4 = reinterpret_cast<const uint4*>(cluster);

    unsigned wcount = 0;                 // wave-uniform queue counter

    #define APPEND(rr, nn)                                                     \
        do {                                                                   \
            bool _p = (rr) < CR;                                               \
            unsigned long long _m = __ballot(_p);                              \
            if (_p) {                                                          \
                unsigned _idx = wcount + (unsigned)__popcll(_m & lml);         \
                if (_idx < WQ) wq[_idx] = (unsigned)(nn);                      \
                else {                                                         \
                    atomicAdd(&bins[(rr)*4+0], x[3*(nn)+0]);                   \
                    atomicAdd(&bins[(rr)*4+1], x[3*(nn)+1]);                   \
                    atomicAdd(&bins[(rr)*4+2], x[3*(nn)+2]);                   \
                    atomicAdd(&bins[(rr)*4+3], 1.f);                           \
                }                                                              \
            }                                                                  \
            wcount += (unsigned)__popcll(_m);                                  \
        } while (0)

    // pass 1: pure streaming scan, 2-deep prefetch, zero barriers
    {
        int i = i0 + tid;
        uint4 c0 = (i          < i1) ? cl4[i]          : make_uint4(~0u,~0u,~0u,~0u);
        uint4 c1 = (i + 512    < i1) ? cl4[i + 512]    : make_uint4(~0u,~0u,~0u,~0u);
        for (int it = 0; it < niter; ++it) {
            uint4 c2 = (i + 1024 < i1) ? cl4[i + 1024] : make_uint4(~0u,~0u,~0u,~0u);
            {
                const int n = i * 4;
                unsigned r0 = c0.x - base, r1 = c0.y - base, r2 = c0.z - base, r3 = c0.w - base;
                APPEND(r0, n + 0);
                APPEND(r1, n + 1);
                APPEND(r2, n + 2);
                APPEND(r3, n + 3);
            }
            c0 = c1; c1 = c2; i += 512;
        }
    }
    #undef APPEND
    if (s == NS - 1) {
        for (int n = P4 * 4 + tid; n < N; n += 512) {
            unsigned rr = (unsigned)cluster[n] - base;
            if (rr < CR) {
                atomicAdd(&bins[rr*4+0], x[3*n+0]);
                atomicAdd(&bins[rr*4+1], x[3*n+1]);
                atomicAdd(&bins[rr*4+2], x[3*n+2]);
                atomicAdd(&bins[rr*4+3], 1.f);
            }
        }
    }

    // per-wave drain
    {
        const unsigned cnt = min(wcount, (unsigned)WQ);
        for (unsigned t = lane; t < cnt; t += 64) {
            unsigned n  = wq[t];
            unsigned rr = (unsigned)cluster[n] - base;
            float x0 = x[3*n+0], x1 = x[3*n+1], x2 = x[3*n+2];
            atomicAdd(&bins[rr*4+0], x0);
            atomicAdd(&bins[rr*4+1], x1);
            atomicAdd(&bins[rr*4+2], x2);
            atomicAdd(&bins[rr*4+3], 1.f);
        }
    }
    __syncthreads();

    ushort4* __restrict__ plane = partials + (size_t)s * K;
    for (int t = tid; t < CR; t += 512) {
        int k = (int)base + t;
        if (k < K) {
            ushort4 u;
            u.x = f2bf(bins[t*4+0]); u.y = f2bf(bins[t*4+1]);
            u.z = f2bf(bins[t*4+2]); u.w = f2bf(bins[t*4+3]);
            plane[k] = u;
        }
    }
}

// ---- stage R: reduce NS bf16 planes -> pooled means; sentinel row at K ----
__global__ void k_reduce(const ushort4* __restrict__ partials, float4* __restrict__ pooled,
                         int K) {
    int k = blockIdx.x * blockDim.x + threadIdx.x;
    if (k < K) {
        float sx = 0.f, sy = 0.f, sz = 0.f, ct = 0.f;
        #pragma unroll
        for (int p = 0; p < NS; ++p) {
            ushort4 u = partials[(size_t)p * K + k];
            sx += bf2f(u.x); sy += bf2f(u.y); sz += bf2f(u.z); ct += bf2f(u.w);
        }
        float inv = 1.0f / fmaxf(ct, 1.0f);
        pooled[k] = make_float4(sx * inv, sy * inv, sz * inv, 0.f);
    } else if (k == K) {
        pooled[K] = make_float4(0.f, 0.f, 0.f, 0.f);
    }
}

// ---- stage C: direct-gather MFMA conv; coalesced stores via LDS transpose ----
__global__ __launch_bounds__(256) void
k_conv(const int* __restrict__ nb, const float4* __restrict__ pooled4,
       const unsigned short* __restrict__ Wpk, const float* __restrict__ b_lin,
       unsigned short* __restrict__ vbf, int K) {
    __shared__ unsigned short xp[64][72];   // 9216 B
    const int tid   = threadIdx.x;
    const int lane  = tid & 63;
    const int wv    = tid >> 6;
    const int m     = lane & 15;
    const int b     = lane >> 4;
    const int cbase = blockIdx.x * 64;
    const int cl    = min(cbase + wv * 16 + m, K - 1);
    const int* __restrict__ nbrow = nb + (size_t)cl * NB;
    const unsigned uK = (unsigned)K;

    bf16x8 bw[12];
    const bf16x8* wp = reinterpret_cast<const bf16x8*>(Wpk);
    #pragma unroll
    for (int st = 0; st < 12; ++st) bw[st] = wp[st * 64 + lane];

    f32x4 acc[4];
    #pragma unroll
    for (int t = 0; t < 4; ++t) {
        float bb = b_lin[16 * t + m];
        acc[t] = (f32x4){bb, bb, bb, bb};
    }

    #pragma unroll
    for (int s = 0; s < 3; ++s) {
        const int K0 = 32 * s + 8 * b;
        const int o0 = K0 / 3;
        const int ph = K0 - 3 * o0;
        float4 P0, P1, P2, P3;
        {
            int o; unsigned idx;
            o = o0 + 0; idx = (o < NB) ? min((unsigned)nbrow[o], uK) : uK; P0 = pooled4[idx];
            o = o0 + 1; idx = (o < NB) ? min((unsigned)nbrow[o], uK) : uK; P1 = pooled4[idx];
            o = o0 + 2; idx = (o < NB) ? min((unsigned)nbrow[o], uK) : uK; P2 = pooled4[idx];
            o = o0 + 3; idx = (o < NB) ? min((unsigned)nbrow[o], uK) : uK; P3 = pooled4[idx];
        }
        bf16x8 af;
        if (ph == 0) {
            af[0] = (short)f2bf(P0.x); af[1] = (short)f2bf(P0.y); af[2] = (short)f2bf(P0.z);
            af[3] = (short)f2bf(P1.x); af[4] = (short)f2bf(P1.y); af[5] = (short)f2bf(P1.z);
            af[6] = (short)f2bf(P2.x); af[7] = (short)f2bf(P2.y);
        } else if (ph == 1) {
            af[0] = (short)f2bf(P0.y); af[1] = (short)f2bf(P0.z);
            af[2] = (short)f2bf(P1.x); af[3] = (short)f2bf(P1.y); af[4] = (short)f2bf(P1.z);
            af[5] = (short)f2bf(P2.x); af[6] = (short)f2bf(P2.y); af[7] = (short)f2bf(P2.z);
        } else {
            af[0] = (short)f2bf(P0.z);
            af[1] = (short)f2bf(P1.x); af[2] = (short)f2bf(P1.y); af[3] = (short)f2bf(P1.z);
            af[4] = (short)f2bf(P2.x); af[5] = (short)f2bf(P2.y); af[6] = (short)f2bf(P2.z);
            af[7] = (short)f2bf(P3.x);
        }
        #pragma unroll
        for (int t = 0; t < 4; ++t)
            acc[t] = __builtin_amdgcn_mfma_f32_16x16x32_bf16(af, bw[s * 4 + t], acc[t], 0, 0, 0);
    }

    #pragma unroll
    for (int t = 0; t < 4; ++t) {
        #pragma unroll
        for (int r = 0; r < 4; ++r)
            xp[wv * 16 + 4 * b + r][16 * t + m] = f2bf(acc[t][r]);
    }
    __syncthreads();
    #pragma unroll
    for (int it = 0; it < 2; ++it) {
        const int idx  = tid + it * 256;
        const int row  = idx >> 3;
        const int ch   = (idx & 7) * 8;
        const int crow = cbase + row;
        if (crow < K) {
            uint4 val = *reinterpret_cast<const uint4*>(&xp[row][ch]);
            *reinterpret_cast<uint4*>(vbf + (size_t)crow * OUT_C + ch) = val;
        }
    }
}

// ---- stage D: one-shot, 8 lanes/point (measured 63.5us, ~90% of floor) ----
__global__ __launch_bounds__(256) void
k_point(const float* __restrict__ x, const int* __restrict__ cluster,
        const unsigned short* __restrict__ vbf, const float* __restrict__ Wl,
        float* __restrict__ out, int N) {
    const int tid = blockIdx.x * 256 + threadIdx.x;
    const int n   = tid >> 3;
    const int jj  = (tid & 7) * 8;
    if (n >= N) return;

    const int c  = cluster[n];
    const float x0 = x[n * 3 + 0];
    const float x1 = x[n * 3 + 1];
    const float x2 = x[n * 3 + 2];

    const float4 w0a = *reinterpret_cast<const float4*>(Wl + 0 * OUT_C + jj);
    const float4 w0b = *reinterpret_cast<const float4*>(Wl + 0 * OUT_C + jj + 4);
    const float4 w1a = *reinterpret_cast<const float4*>(Wl + 1 * OUT_C + jj);
    const float4 w1b = *reinterpret_cast<const float4*>(Wl + 1 * OUT_C + jj + 4);
    const float4 w2a = *reinterpret_cast<const float4*>(Wl + 2 * OUT_C + jj);
    const float4 w2b = *reinterpret_cast<const float4*>(Wl + 2 * OUT_C + jj + 4);

    const uint4 vr = *reinterpret_cast<const uint4*>(vbf + (size_t)c * OUT_C + jj);

    f32x4 oa, ob;
    oa[0] = fmaf(x0, w0a.x, fmaf(x1, w1a.x, fmaf(x2, w2a.x, bflo(vr.x))));
    oa[1] = fmaf(x0, w0a.y, fmaf(x1, w1a.y, fmaf(x2, w2a.y, bfhi(vr.x))));
    oa[2] = fmaf(x0, w0a.z, fmaf(x1, w1a.z, fmaf(x2, w2a.z, bflo(vr.y))));
    oa[3] = fmaf(x0, w0a.w, fmaf(x1, w1a.w, fmaf(x2, w2a.w, bfhi(vr.y))));
    ob[0] = fmaf(x0, w0b.x, fmaf(x1, w1b.x, fmaf(x2, w2b.x, bflo(vr.z))));
    ob[1] = fmaf(x0, w0b.y, fmaf(x1, w1b.y, fmaf(x2, w2b.y, bfhi(vr.z))));
    ob[2] = fmaf(x0, w0b.z, fmaf(x1, w1b.z, fmaf(x2, w2b.z, bflo(vr.w))));
    ob[3] = fmaf(x0, w0b.w, fmaf(x1, w1b.w, fmaf(x2, w2b.w, bfhi(vr.w))));

    float* op = out + (size_t)n * OUT_C + jj;
    *reinterpret_cast<f32x4*>(op)     = oa;
    *reinterpret_cast<f32x4*>(op + 4) = ob;
}

extern "C" void kernel_launch(void* const* d_in, const int* in_sizes, int n_in,
                              void* d_out, int out_size, void* d_ws, size_t ws_size,
                              hipStream_t stream) {
    const float* x      = (const float*)d_in[0];
    const int*   cluster= (const int*)  d_in[1];
    const int*   nb     = (const int*)  d_in[2];
    const float* W_conv = (const float*)d_in[3];
    const float* W_lin  = (const float*)d_in[4];
    const float* b_lin  = (const float*)d_in[5];
    float* out = (float*)d_out;

    const int N = in_sizes[1];         // 1,000,000
    const int K = in_sizes[2] / NB;    // 200,000

    // workspace layout
    char* ws = (char*)d_ws;
    float4* pooled4 = (float4*)ws;                     // (K+1) * 16 B (sentinel at K)
    size_t off = (size_t)(K + 1) * sizeof(float4);
    off = ((off + 255) / 256) * 256;
    unsigned short* Wpk = (unsigned short*)(ws + off); // 12.3 KB packed bf16 weights
    off += ((WPK_N * sizeof(unsigned short) + 255) / 256) * 256;
    ushort4* partials = (ushort4*)(ws + off);
    unsigned short* vbf = (unsigned short*)(ws + off);

    const int R = (K + CR - 1) / CR;                   // 25 ranges
    k_poolscan<<<R * NS + 1, 512, 0, stream>>>(cluster, x, partials, N, K, R,
                                               W_conv, W_lin, Wpk);
    k_reduce<<<(K + 1 + 255) / 256, 256, 0, stream>>>(partials, pooled4, K);

    const int conv_blocks = (K + 63) / 64;             // 3125
    // MEASUREMENT ROUND: k_conv launched TWICE (idempotent pure-overwrite).
    // dur_us - 161.9 = one k_conv duration. Output bit-identical.
    k_conv<<<conv_blocks, 256, 0, stream>>>(nb, pooled4, Wpk, b_lin, vbf, K);
    k_conv<<<conv_blocks, 256, 0, stream>>>(nb, pooled4, Wpk, b_lin, vbf, K);

    const int point_blocks = (N * 8 + 255) / 256;      // 31250
    k_point<<<point_blocks, 256, 0, stream>>>(x, cluster, vbf, W_lin, out, N);
}

// Round 24
// 157.337 us; speedup vs baseline: 1.2626x; 1.2626x over previous
//
#include <hip/hip_runtime.h>

constexpr int IN_C   = 3;
constexpr int OUT_C  = 64;
constexpr int NB     = 27;
constexpr int CR     = 8192;             // clusters per range (128 KB LDS bins)
constexpr int NS     = 10;               // point slices; R*NS = 250 blocks (1/CU)
constexpr int WQ     = 768;              // per-wave queue entries (mean 514 + 11 sigma)
constexpr int NW     = 8;                // waves per poolscan block (512 threads)
constexpr int WPK_N  = 12 * 64 * 8;      // 6144 bf16 fragment elements

typedef float f32x4 __attribute__((ext_vector_type(4)));
typedef short bf16x8 __attribute__((ext_vector_type(8)));

__device__ __forceinline__ unsigned short f2bf(float f) {
    unsigned u = __builtin_bit_cast(unsigned, f);
    u += 0x7fffu + ((u >> 16) & 1u);     // round-to-nearest-even
    return (unsigned short)(u >> 16);
}
__device__ __forceinline__ float bf2f(unsigned short v) {
    return __builtin_bit_cast(float, (unsigned)v << 16);
}
__device__ __forceinline__ float bflo(unsigned u) {
    return __builtin_bit_cast(float, u << 16);
}
__device__ __forceinline__ float bfhi(unsigned u) {
    return __builtin_bit_cast(float, u & 0xffff0000u);
}

// ---- stage A (+fold in last block): range binning, per-wave queues ----
__global__ __launch_bounds__(512) void
k_poolscan(const int* __restrict__ cluster, const float* __restrict__ x,
           ushort4* __restrict__ partials, int N, int K, int R,
           const float* __restrict__ Wc, const float* __restrict__ Wl,
           unsigned short* __restrict__ Wpk) {
    // ---- fold block: pack W_conv @ W_lin[3:,:] into MFMA B-fragment order ----
    if (blockIdx.x >= (unsigned)(R * NS)) {
        for (int t = threadIdx.x; t < WPK_N; t += 512) {
            int j  = t & 7;
            int l  = (t >> 3) & 63;
            int st = t >> 9;
            int s  = st >> 2, tt = st & 3;
            int kk = 32 * s + 8 * (l >> 4) + j;
            int ch = 16 * tt + (l & 15);
            float acc = 0.f;
            if (kk < NB * IN_C) {
                #pragma unroll
                for (int j2 = 0; j2 < OUT_C; ++j2)
                    acc = fmaf(Wc[kk * 64 + j2], Wl[(IN_C + j2) * OUT_C + ch], acc);
            }
            Wpk[t] = f2bf(acc);
        }
        return;
    }

    __shared__ float bins[CR * 4];       // 128 KB
    __shared__ unsigned qbuf[NW * WQ];   // 24.5 KB: per-wave slices
    const int tid  = threadIdx.x;
    const int wv   = tid >> 6;
    const int lane = tid & 63;
    const int r    = blockIdx.x % R;
    const int s    = blockIdx.x / R;
    const unsigned base = (unsigned)r * CR;
    const unsigned long long lml = (1ull << lane) - 1ull;   // lanemask_lt
    unsigned* __restrict__ wq = qbuf + wv * WQ;

    for (int i = tid; i < CR * 4; i += 512) bins[i] = 0.f;
    __syncthreads();

    const int P4 = N >> 2;               // uint4 count
    const int Q  = P4 / NS;
    const int i0 = s * Q;
    const int i1 = (s == NS - 1) ? P4 : (s + 1) * Q;
    const int niter = (i1 - i0 + 511) >> 9;
    const uint4* __restrict__ cl4 = reinterpret_cast<const uint4*>(cluster);

    unsigned wcount = 0;                 // wave-uniform queue counter

    #define APPEND(rr, nn)                                                     \
        do {                                                                   \
            bool _p = (rr) < CR;                                               \
            unsigned long long _m = __ballot(_p);                              \
            if (_p) {                                                          \
                unsigned _idx = wcount + (unsigned)__popcll(_m & lml);         \
                if (_idx < WQ) wq[_idx] = (unsigned)(nn);                      \
                else {                                                         \
                    atomicAdd(&bins[(rr)*4+0], x[3*(nn)+0]);                   \
                    atomicAdd(&bins[(rr)*4+1], x[3*(nn)+1]);                   \
                    atomicAdd(&bins[(rr)*4+2], x[3*(nn)+2]);                   \
                    atomicAdd(&bins[(rr)*4+3], 1.f);                           \
                }                                                              \
            }                                                                  \
            wcount += (unsigned)__popcll(_m);                                  \
        } while (0)

    // pass 1: pure streaming scan, 2-deep prefetch, zero barriers
    {
        int i = i0 + tid;
        uint4 c0 = (i          < i1) ? cl4[i]          : make_uint4(~0u,~0u,~0u,~0u);
        uint4 c1 = (i + 512    < i1) ? cl4[i + 512]    : make_uint4(~0u,~0u,~0u,~0u);
        for (int it = 0; it < niter; ++it) {
            uint4 c2 = (i + 1024 < i1) ? cl4[i + 1024] : make_uint4(~0u,~0u,~0u,~0u);
            {
                const int n = i * 4;
                unsigned r0 = c0.x - base, r1 = c0.y - base, r2 = c0.z - base, r3 = c0.w - base;
                APPEND(r0, n + 0);
                APPEND(r1, n + 1);
                APPEND(r2, n + 2);
                APPEND(r3, n + 3);
            }
            c0 = c1; c1 = c2; i += 512;
        }
    }
    #undef APPEND
    if (s == NS - 1) {
        for (int n = P4 * 4 + tid; n < N; n += 512) {
            unsigned rr = (unsigned)cluster[n] - base;
            if (rr < CR) {
                atomicAdd(&bins[rr*4+0], x[3*n+0]);
                atomicAdd(&bins[rr*4+1], x[3*n+1]);
                atomicAdd(&bins[rr*4+2], x[3*n+2]);
                atomicAdd(&bins[rr*4+3], 1.f);
            }
        }
    }

    // per-wave drain
    {
        const unsigned cnt = min(wcount, (unsigned)WQ);
        for (unsigned t = lane; t < cnt; t += 64) {
            unsigned n  = wq[t];
            unsigned rr = (unsigned)cluster[n] - base;
            float x0 = x[3*n+0], x1 = x[3*n+1], x2 = x[3*n+2];
            atomicAdd(&bins[rr*4+0], x0);
            atomicAdd(&bins[rr*4+1], x1);
            atomicAdd(&bins[rr*4+2], x2);
            atomicAdd(&bins[rr*4+3], 1.f);
        }
    }
    __syncthreads();

    ushort4* __restrict__ plane = partials + (size_t)s * K;
    for (int t = tid; t < CR; t += 512) {
        int k = (int)base + t;
        if (k < K) {
            ushort4 u;
            u.x = f2bf(bins[t*4+0]); u.y = f2bf(bins[t*4+1]);
            u.z = f2bf(bins[t*4+2]); u.w = f2bf(bins[t*4+3]);
            plane[k] = u;
        }
    }
}

// ---- stage R: reduce NS bf16 planes -> pooled means; sentinel row at K ----
__global__ void k_reduce(const ushort4* __restrict__ partials, float4* __restrict__ pooled,
                         int K) {
    int k = blockIdx.x * blockDim.x + threadIdx.x;
    if (k < K) {
        float sx = 0.f, sy = 0.f, sz = 0.f, ct = 0.f;
        #pragma unroll
        for (int p = 0; p < NS; ++p) {
            ushort4 u = partials[(size_t)p * K + k];
            sx += bf2f(u.x); sy += bf2f(u.y); sz += bf2f(u.z); ct += bf2f(u.w);
        }
        float inv = 1.0f / fmaxf(ct, 1.0f);
        pooled[k] = make_float4(sx * inv, sy * inv, sz * inv, 0.f);
    } else if (k == K) {
        pooled[K] = make_float4(0.f, 0.f, 0.f, 0.f);
    }
}

// ---- stage C: MFMA conv with COOPERATIVE COALESCED nb staging ----
// The block's nb slice (64 rows x 27 ints = 27648B) is CONTIGUOUS in memory:
// load it coalesced into LDS (rows padded to 28 -> lane reads are exact 2-way
// bank aliasing = free). Per-lane chain becomes LDS-read -> pooled gather;
// the scattered per-lane nb line-transactions (~3M) disappear.
__global__ __launch_bounds__(256) void
k_conv(const int* __restrict__ nb, const float4* __restrict__ pooled4,
       const unsigned short* __restrict__ Wpk, const float* __restrict__ b_lin,
       unsigned short* __restrict__ vbf, int K) {
    __shared__ int nbs[64 * 28];            // 7168 B, padded rows
    __shared__ unsigned short xp[64][72];   // 9216 B
    const int tid   = threadIdx.x;
    const int lane  = tid & 63;
    const int wv    = tid >> 6;
    const int m     = lane & 15;
    const int b     = lane >> 4;
    const int cbase = blockIdx.x * 64;
    const int nrows = min(64, K - cbase);
    const unsigned uK = (unsigned)K;

    // phase 1: coalesced nb staging (contiguous source region)
    {
        const int total = nrows * NB;
        const int* src = nb + (size_t)cbase * NB;
        for (int t = tid; t < total; t += 256) {
            int row = t / NB, o = t - row * NB;
            nbs[row * 28 + o] = src[t];
        }
    }
    __syncthreads();

    const int lc = min(wv * 16 + m, nrows - 1);
    const int* __restrict__ nbrow = nbs + lc * 28;

    bf16x8 bw[12];
    const bf16x8* wp = reinterpret_cast<const bf16x8*>(Wpk);
    #pragma unroll
    for (int st = 0; st < 12; ++st) bw[st] = wp[st * 64 + lane];

    f32x4 acc[4];
    #pragma unroll
    for (int t = 0; t < 4; ++t) {
        float bb = b_lin[16 * t + m];
        acc[t] = (f32x4){bb, bb, bb, bb};
    }

    #pragma unroll
    for (int s = 0; s < 3; ++s) {
        const int K0 = 32 * s + 8 * b;
        const int o0 = K0 / 3;
        const int ph = K0 - 3 * o0;
        float4 P0, P1, P2, P3;
        {
            int o; unsigned idx;
            o = o0 + 0; idx = (o < NB) ? min((unsigned)nbrow[o], uK) : uK; P0 = pooled4[idx];
            o = o0 + 1; idx = (o < NB) ? min((unsigned)nbrow[o], uK) : uK; P1 = pooled4[idx];
            o = o0 + 2; idx = (o < NB) ? min((unsigned)nbrow[o], uK) : uK; P2 = pooled4[idx];
            o = o0 + 3; idx = (o < NB) ? min((unsigned)nbrow[o], uK) : uK; P3 = pooled4[idx];
        }
        bf16x8 af;
        if (ph == 0) {
            af[0] = (short)f2bf(P0.x); af[1] = (short)f2bf(P0.y); af[2] = (short)f2bf(P0.z);
            af[3] = (short)f2bf(P1.x); af[4] = (short)f2bf(P1.y); af[5] = (short)f2bf(P1.z);
            af[6] = (short)f2bf(P2.x); af[7] = (short)f2bf(P2.y);
        } else if (ph == 1) {
            af[0] = (short)f2bf(P0.y); af[1] = (short)f2bf(P0.z);
            af[2] = (short)f2bf(P1.x); af[3] = (short)f2bf(P1.y); af[4] = (short)f2bf(P1.z);
            af[5] = (short)f2bf(P2.x); af[6] = (short)f2bf(P2.y); af[7] = (short)f2bf(P2.z);
        } else {
            af[0] = (short)f2bf(P0.z);
            af[1] = (short)f2bf(P1.x); af[2] = (short)f2bf(P1.y); af[3] = (short)f2bf(P1.z);
            af[4] = (short)f2bf(P2.x); af[5] = (short)f2bf(P2.y); af[6] = (short)f2bf(P2.z);
            af[7] = (short)f2bf(P3.x);
        }
        #pragma unroll
        for (int t = 0; t < 4; ++t)
            acc[t] = __builtin_amdgcn_mfma_f32_16x16x32_bf16(af, bw[s * 4 + t], acc[t], 0, 0, 0);
    }

    #pragma unroll
    for (int t = 0; t < 4; ++t) {
        #pragma unroll
        for (int r = 0; r < 4; ++r)
            xp[wv * 16 + 4 * b + r][16 * t + m] = f2bf(acc[t][r]);
    }
    __syncthreads();
    #pragma unroll
    for (int it = 0; it < 2; ++it) {
        const int idx  = tid + it * 256;
        const int row  = idx >> 3;
        const int ch   = (idx & 7) * 8;
        const int crow = cbase + row;
        if (crow < K) {
            uint4 val = *reinterpret_cast<const uint4*>(&xp[row][ch]);
            *reinterpret_cast<uint4*>(vbf + (size_t)crow * OUT_C + ch) = val;
        }
    }
}

// ---- stage D: one-shot, 8 lanes/point (measured 63.5us, ~90% of floor) ----
__global__ __launch_bounds__(256) void
k_point(const float* __restrict__ x, const int* __restrict__ cluster,
        const unsigned short* __restrict__ vbf, const float* __restrict__ Wl,
        float* __restrict__ out, int N) {
    const int tid = blockIdx.x * 256 + threadIdx.x;
    const int n   = tid >> 3;
    const int jj  = (tid & 7) * 8;
    if (n >= N) return;

    const int c  = cluster[n];
    const float x0 = x[n * 3 + 0];
    const float x1 = x[n * 3 + 1];
    const float x2 = x[n * 3 + 2];

    const float4 w0a = *reinterpret_cast<const float4*>(Wl + 0 * OUT_C + jj);
    const float4 w0b = *reinterpret_cast<const float4*>(Wl + 0 * OUT_C + jj + 4);
    const float4 w1a = *reinterpret_cast<const float4*>(Wl + 1 * OUT_C + jj);
    const float4 w1b = *reinterpret_cast<const float4*>(Wl + 1 * OUT_C + jj + 4);
    const float4 w2a = *reinterpret_cast<const float4*>(Wl + 2 * OUT_C + jj);
    const float4 w2b = *reinterpret_cast<const float4*>(Wl + 2 * OUT_C + jj + 4);

    const uint4 vr = *reinterpret_cast<const uint4*>(vbf + (size_t)c * OUT_C + jj);

    f32x4 oa, ob;
    oa[0] = fmaf(x0, w0a.x, fmaf(x1, w1a.x, fmaf(x2, w2a.x, bflo(vr.x))));
    oa[1] = fmaf(x0, w0a.y, fmaf(x1, w1a.y, fmaf(x2, w2a.y, bfhi(vr.x))));
    oa[2] = fmaf(x0, w0a.z, fmaf(x1, w1a.z, fmaf(x2, w2a.z, bflo(vr.y))));
    oa[3] = fmaf(x0, w0a.w, fmaf(x1, w1a.w, fmaf(x2, w2a.w, bfhi(vr.y))));
    ob[0] = fmaf(x0, w0b.x, fmaf(x1, w1b.x, fmaf(x2, w2b.x, bflo(vr.z))));
    ob[1] = fmaf(x0, w0b.y, fmaf(x1, w1b.y, fmaf(x2, w2b.y, bfhi(vr.z))));
    ob[2] = fmaf(x0, w0b.z, fmaf(x1, w1b.z, fmaf(x2, w2b.z, bflo(vr.w))));
    ob[3] = fmaf(x0, w0b.w, fmaf(x1, w1b.w, fmaf(x2, w2b.w, bfhi(vr.w))));

    float* op = out + (size_t)n * OUT_C + jj;
    *reinterpret_cast<f32x4*>(op)     = oa;
    *reinterpret_cast<f32x4*>(op + 4) = ob;
}

extern "C" void kernel_launch(void* const* d_in, const int* in_sizes, int n_in,
                              void* d_out, int out_size, void* d_ws, size_t ws_size,
                              hipStream_t stream) {
    const float* x      = (const float*)d_in[0];
    const int*   cluster= (const int*)  d_in[1];
    const int*   nb     = (const int*)  d_in[2];
    const float* W_conv = (const float*)d_in[3];
    const float* W_lin  = (const float*)d_in[4];
    const float* b_lin  = (const float*)d_in[5];
    float* out = (float*)d_out;

    const int N = in_sizes[1];         // 1,000,000
    const int K = in_sizes[2] / NB;    // 200,000

    // workspace layout
    char* ws = (char*)d_ws;
    float4* pooled4 = (float4*)ws;                     // (K+1) * 16 B (sentinel at K)
    size_t off = (size_t)(K + 1) * sizeof(float4);
    off = ((off + 255) / 256) * 256;
    unsigned short* Wpk = (unsigned short*)(ws + off); // 12.3 KB packed bf16 weights
    off += ((WPK_N * sizeof(unsigned short) + 255) / 256) * 256;
    ushort4* partials = (ushort4*)(ws + off);
    unsigned short* vbf = (unsigned short*)(ws + off);

    const int R = (K + CR - 1) / CR;                   // 25 ranges
    k_poolscan<<<R * NS + 1, 512, 0, stream>>>(cluster, x, partials, N, K, R,
                                               W_conv, W_lin, Wpk);
    k_reduce<<<(K + 1 + 255) / 256, 256, 0, stream>>>(partials, pooled4, K);

    const int conv_blocks = (K + 63) / 64;             // 3125
    k_conv<<<conv_blocks, 256, 0, stream>>>(nb, pooled4, Wpk, b_lin, vbf, K);

    const int point_blocks = (N * 8 + 255) / 256;      // 31250
    k_point<<<point_blocks, 256, 0, stream>>>(x, cluster, vbf, W_lin, out, N);
}